// Round 2
// baseline (3178.486 us; speedup 1.0000x reference)
//
#include <hip/hip_runtime.h>
#include <stdint.h>

#define NN   50000
#define INC  512
#define OUTC 128

// ---------------- degree ----------------
__global__ __launch_bounds__(256) void k_init_deg(float* __restrict__ deg) {
  int i = blockIdx.x * 256 + threadIdx.x;
  if (i < NN) deg[i] = 1.0f;  // self-loop
}

__global__ __launch_bounds__(256) void k_count_deg(const int* __restrict__ dst, int E,
                                                   float* __restrict__ deg) {
  int e = blockIdx.x * 256 + threadIdx.x;
  if (e < E) atomicAdd(&deg[dst[e]], 1.0f);
}

__global__ __launch_bounds__(256) void k_rsqrt(float* __restrict__ deg) {
  int i = blockIdx.x * 256 + threadIdx.x;
  if (i < NN) deg[i] = rsqrtf(deg[i]);  // deg >= 1 always (self-loops)
}

// ---------------- GEMM1: xw = x @ W_enc  (fp32, 64x128 tile) ----------------
__global__ __launch_bounds__(256) void k_gemm1(const float* __restrict__ x,
                                               const float* __restrict__ W,
                                               float* __restrict__ xw) {
  __shared__ float As[16][65];    // [k][row], padded
  __shared__ float Bs[16][128];   // [k][col]
  const int tid  = threadIdx.x;
  const int rb   = blockIdx.x * 64;
  const int tcol = tid & 15, trow = tid >> 4;
  const int c0 = tcol * 8, r0 = trow * 4;

  float4 acc[4][2];
#pragma unroll
  for (int i = 0; i < 4; i++) {
    acc[i][0] = make_float4(0.f, 0.f, 0.f, 0.f);
    acc[i][1] = make_float4(0.f, 0.f, 0.f, 0.f);
  }

  const int lrow = tid >> 2, lk = (tid & 3) * 4;
  int arow = rb + lrow; if (arow >= NN) arow = NN - 1;   // clamp (stores guarded)
  const float* xp = x + (size_t)arow * INC + lk;
  const int bk = tid >> 5, bc = (tid & 31) * 4;

  for (int k0 = 0; k0 < INC; k0 += 16) {
    float4 av  = *(const float4*)(xp + k0);
    float4 bv0 = *(const float4*)(W + (size_t)(k0 + bk) * OUTC + bc);
    float4 bv1 = *(const float4*)(W + (size_t)(k0 + bk + 8) * OUTC + bc);
    __syncthreads();
    As[lk + 0][lrow] = av.x; As[lk + 1][lrow] = av.y;
    As[lk + 2][lrow] = av.z; As[lk + 3][lrow] = av.w;
    *(float4*)&Bs[bk][bc]     = bv0;
    *(float4*)&Bs[bk + 8][bc] = bv1;
    __syncthreads();
#pragma unroll
    for (int kk = 0; kk < 16; kk++) {
      float4 b0 = *(float4*)&Bs[kk][c0];
      float4 b1 = *(float4*)&Bs[kk][c0 + 4];
#pragma unroll
      for (int i = 0; i < 4; i++) {
        float a = As[kk][r0 + i];
        acc[i][0].x += a * b0.x; acc[i][0].y += a * b0.y;
        acc[i][0].z += a * b0.z; acc[i][0].w += a * b0.w;
        acc[i][1].x += a * b1.x; acc[i][1].y += a * b1.y;
        acc[i][1].z += a * b1.z; acc[i][1].w += a * b1.w;
      }
    }
  }
#pragma unroll
  for (int i = 0; i < 4; i++) {
    int row = rb + r0 + i;
    if (row < NN) {
      *(float4*)(xw + (size_t)row * OUTC + c0)     = acc[i][0];
      *(float4*)(xw + (size_t)row * OUTC + c0 + 4) = acc[i][1];
    }
  }
}

// ---------------- z init: bias + self-loop term ----------------
__global__ __launch_bounds__(256) void k_init_z(const float* __restrict__ xw,
                                                const float* __restrict__ dis,
                                                const float* __restrict__ b,
                                                float* __restrict__ z) {
  int gid = blockIdx.x * 256 + threadIdx.x;
  if (gid >= NN * 32) return;
  int i = gid >> 5, q = (gid & 31) * 4;
  float s = dis[i]; s = s * s;
  float4 v  = *(const float4*)(xw + (size_t)i * OUTC + q);
  float4 bb = *(const float4*)(b + q);
  float4 o;
  o.x = bb.x + v.x * s; o.y = bb.y + v.y * s;
  o.z = bb.z + v.z * s; o.w = bb.w + v.w * s;
  *(float4*)(z + (size_t)i * OUTC + q) = o;
}

// ---------------- edge scatter: z[dst] += xw[src] * norm ----------------
__global__ __launch_bounds__(256) void k_scatter(const float* __restrict__ xw,
                                                 const float* __restrict__ dis,
                                                 const int* __restrict__ src,
                                                 const int* __restrict__ dst,
                                                 int E, float* __restrict__ z) {
  long gid = (long)blockIdx.x * 256 + threadIdx.x;
  if (gid >= (long)E * 32) return;
  int e = (int)(gid >> 5), q = ((int)gid & 31) * 4;
  int s = src[e], d = dst[e];
  float nrm = dis[s] * dis[d];
  float4 v = *(const float4*)(xw + (size_t)s * OUTC + q);
  float* zp = z + (size_t)d * OUTC + q;
  atomicAdd(zp + 0, v.x * nrm);
  atomicAdd(zp + 1, v.y * nrm);
  atomicAdd(zp + 2, v.z * nrm);
  atomicAdd(zp + 3, v.w * nrm);
}

// ---------------- decode: relu -> z @ W_dec -> softmax ----------------
__global__ __launch_bounds__(256) void k_decode(const float* __restrict__ z,
                                                const float* __restrict__ Wd,
                                                float* __restrict__ out) {
  __shared__ float zs[16 * 128];   // 8 KB  (relu'd z rows, 16 nodes)
  __shared__ float lg[16 * 512];   // 32 KB (logits)
  const int tid = threadIdx.x;
  const size_t nb = (size_t)blockIdx.x * 16;

  const float4* zsrc = (const float4*)(z + nb * OUTC);
#pragma unroll
  for (int i = 0; i < 2; i++) {
    float4 v = zsrc[tid + i * 256];
    v.x = fmaxf(v.x, 0.f); v.y = fmaxf(v.y, 0.f);
    v.z = fmaxf(v.z, 0.f); v.w = fmaxf(v.w, 0.f);
    *(float4*)&zs[(tid + i * 256) * 4] = v;
  }
  __syncthreads();

  float acc0[16], acc1[16];
#pragma unroll
  for (int n = 0; n < 16; n++) { acc0[n] = 0.f; acc1[n] = 0.f; }

  for (int k = 0; k < 128; k += 4) {
    float w0[4], w1[4];
#pragma unroll
    for (int j = 0; j < 4; j++) {
      w0[j] = Wd[(size_t)(k + j) * INC + tid];
      w1[j] = Wd[(size_t)(k + j) * INC + tid + 256];
    }
#pragma unroll
    for (int n = 0; n < 16; n++) {
      float4 zk = *(float4*)&zs[n * OUTC + k];
      acc0[n] += zk.x * w0[0] + zk.y * w0[1] + zk.z * w0[2] + zk.w * w0[3];
      acc1[n] += zk.x * w1[0] + zk.y * w1[1] + zk.z * w1[2] + zk.w * w1[3];
    }
  }

#pragma unroll
  for (int n = 0; n < 16; n++) {
    lg[n * INC + tid]       = acc0[n];
    lg[n * INC + tid + 256] = acc1[n];
  }
  __syncthreads();

  const int wid = tid >> 6, lane = tid & 63;
  for (int n = wid * 4; n < wid * 4 + 4; n++) {
    float v[8]; float m = -1e30f;
#pragma unroll
    for (int i = 0; i < 8; i++) { v[i] = lg[n * INC + lane + i * 64]; m = fmaxf(m, v[i]); }
#pragma unroll
    for (int off = 32; off > 0; off >>= 1) m = fmaxf(m, __shfl_xor(m, off));
    float ssum = 0.f;
#pragma unroll
    for (int i = 0; i < 8; i++) { v[i] = __expf(v[i] - m); ssum += v[i]; }
#pragma unroll
    for (int off = 32; off > 0; off >>= 1) ssum += __shfl_xor(ssum, off);
    float inv = 1.0f / ssum;
    float* op = out + (nb + n) * INC;
#pragma unroll
    for (int i = 0; i < 8; i++) op[lane + i * 64] = v[i] * inv;
  }
}

// ---------------- launch ----------------
extern "C" void kernel_launch(void* const* d_in, const int* in_sizes, int n_in,
                              void* d_out, int out_size, void* d_ws, size_t ws_size,
                              hipStream_t stream) {
  const float* x     = (const float*)d_in[0];
  const int*   ei    = (const int*)d_in[1];
  const float* W_enc = (const float*)d_in[2];
  const float* b_enc = (const float*)d_in[3];
  const float* W_dec = (const float*)d_in[4];
  float* out = (float*)d_out;

  const int E = in_sizes[1] / 2;
  const int* esrc = ei;
  const int* edst = ei + E;

  uint8_t* ws = (uint8_t*)d_ws;
  float* deg = (float*)ws;                                   // 200 KB
  float* xw  = (float*)(ws + (1 << 18));                     // 25.6 MB
  float* z   = (float*)(ws + (1 << 18) + 25600000);          // 25.6 MB

  k_init_deg <<<(NN + 255) / 256, 256, 0, stream>>>(deg);
  k_count_deg<<<(E + 255) / 256, 256, 0, stream>>>(edst, E, deg);
  k_rsqrt    <<<(NN + 255) / 256, 256, 0, stream>>>(deg);
  k_gemm1    <<<(NN + 63) / 64, 256, 0, stream>>>(x, W_enc, xw);
  k_init_z   <<<(NN * 32 + 255) / 256, 256, 0, stream>>>(xw, deg, b_enc, z);
  k_scatter  <<<(int)(((long)E * 32 + 255) / 256), 256, 0, stream>>>(xw, deg, esrc, edst, E, z);
  k_decode   <<<NN / 16, 256, 0, stream>>>(z, W_dec, out);
}

// Round 3
// 799.251 us; speedup vs baseline: 3.9768x; 3.9768x over previous
//
#include <hip/hip_runtime.h>
#include <stdint.h>

#define NN   50000
#define INC  512
#define OUTC 128
#define SCAN_T  1024
#define SCAN_CH 49   // 1024*49 = 50176 >= NN

// ---------------- degree / norm ----------------
__global__ __launch_bounds__(256) void k_zero_cnt(int* __restrict__ c) {
  int i = blockIdx.x * 256 + threadIdx.x;
  if (i < NN) c[i] = 0;
}

__global__ __launch_bounds__(256) void k_count(const int* __restrict__ dst, int E,
                                               int* __restrict__ cnt) {
  int e = blockIdx.x * 256 + threadIdx.x;
  if (e < E) atomicAdd(&cnt[dst[e]], 1);
}

__global__ __launch_bounds__(256) void k_dis(const int* __restrict__ cnt,
                                             float* __restrict__ dis) {
  int i = blockIdx.x * 256 + threadIdx.x;
  if (i < NN) dis[i] = rsqrtf((float)(cnt[i] + 1));  // +1 self-loop
}

// ---------------- CSR build ----------------
__global__ __launch_bounds__(SCAN_T) void k_scan(const int* __restrict__ cnt,
                                                 int* __restrict__ row_start,
                                                 int* __restrict__ cursor) {
  __shared__ int part[SCAN_T];
  const int tid = threadIdx.x;
  const int base = tid * SCAN_CH;
  int s = 0;
  for (int j = 0; j < SCAN_CH; j++) {
    int idx = base + j;
    if (idx < NN) s += cnt[idx];
  }
  part[tid] = s;
  __syncthreads();
  for (int off = 1; off < SCAN_T; off <<= 1) {
    int v = (tid >= off) ? part[tid - off] : 0;
    __syncthreads();
    part[tid] += v;
    __syncthreads();
  }
  int run = (tid == 0) ? 0 : part[tid - 1];  // exclusive prefix of this chunk
  for (int j = 0; j < SCAN_CH; j++) {
    int idx = base + j;
    if (idx < NN) {
      row_start[idx] = run;
      cursor[idx]    = run;
      run += cnt[idx];
    }
  }
  if (tid == SCAN_T - 1) row_start[NN] = run;  // = E
}

__global__ __launch_bounds__(256) void k_fill(const int* __restrict__ src,
                                              const int* __restrict__ dst, int E,
                                              int* __restrict__ cursor,
                                              int* __restrict__ csr_src) {
  int e = blockIdx.x * 256 + threadIdx.x;
  if (e >= E) return;
  int d = dst[e];
  int pos = atomicAdd(&cursor[d], 1);
  csr_src[pos] = src[e];
}

// ---------------- GEMM1: xws = (x @ W_enc) * dis[row]  (fp32, 64x128 tile) ----------------
__global__ __launch_bounds__(256) void k_gemm1(const float* __restrict__ x,
                                               const float* __restrict__ W,
                                               const float* __restrict__ dis,
                                               float* __restrict__ xws) {
  __shared__ float As[16][65];    // [k][row], padded
  __shared__ float Bs[16][128];   // [k][col]
  const int tid  = threadIdx.x;
  const int rb   = blockIdx.x * 64;
  const int tcol = tid & 15, trow = tid >> 4;
  const int c0 = tcol * 8, r0 = trow * 4;

  float4 acc[4][2];
#pragma unroll
  for (int i = 0; i < 4; i++) {
    acc[i][0] = make_float4(0.f, 0.f, 0.f, 0.f);
    acc[i][1] = make_float4(0.f, 0.f, 0.f, 0.f);
  }

  const int lrow = tid >> 2, lk = (tid & 3) * 4;
  int arow = rb + lrow; if (arow >= NN) arow = NN - 1;   // clamp (stores guarded)
  const float* xp = x + (size_t)arow * INC + lk;
  const int bk = tid >> 5, bc = (tid & 31) * 4;

  for (int k0 = 0; k0 < INC; k0 += 16) {
    float4 av  = *(const float4*)(xp + k0);
    float4 bv0 = *(const float4*)(W + (size_t)(k0 + bk) * OUTC + bc);
    float4 bv1 = *(const float4*)(W + (size_t)(k0 + bk + 8) * OUTC + bc);
    __syncthreads();
    As[lk + 0][lrow] = av.x; As[lk + 1][lrow] = av.y;
    As[lk + 2][lrow] = av.z; As[lk + 3][lrow] = av.w;
    *(float4*)&Bs[bk][bc]     = bv0;
    *(float4*)&Bs[bk + 8][bc] = bv1;
    __syncthreads();
#pragma unroll
    for (int kk = 0; kk < 16; kk++) {
      float4 b0 = *(float4*)&Bs[kk][c0];
      float4 b1 = *(float4*)&Bs[kk][c0 + 4];
#pragma unroll
      for (int i = 0; i < 4; i++) {
        float a = As[kk][r0 + i];
        acc[i][0].x += a * b0.x; acc[i][0].y += a * b0.y;
        acc[i][0].z += a * b0.z; acc[i][0].w += a * b0.w;
        acc[i][1].x += a * b1.x; acc[i][1].y += a * b1.y;
        acc[i][1].z += a * b1.z; acc[i][1].w += a * b1.w;
      }
    }
  }
#pragma unroll
  for (int i = 0; i < 4; i++) {
    int row = rb + r0 + i;
    if (row < NN) {
      float dv = dis[row];
      float4 o0 = acc[i][0], o1 = acc[i][1];
      o0.x *= dv; o0.y *= dv; o0.z *= dv; o0.w *= dv;
      o1.x *= dv; o1.y *= dv; o1.z *= dv; o1.w *= dv;
      *(float4*)(xws + (size_t)row * OUTC + c0)     = o0;
      *(float4*)(xws + (size_t)row * OUTC + c0 + 4) = o1;
    }
  }
}

// ---------------- aggregate: z[i] = relu(dis[i]*(sum_j xws[src_j] + xws[i]) + b) ----------------
__global__ __launch_bounds__(128) void k_aggregate(const float* __restrict__ xws,
                                                   const float* __restrict__ dis,
                                                   const int* __restrict__ row_start,
                                                   const int* __restrict__ csr_src,
                                                   const float* __restrict__ b,
                                                   float* __restrict__ z) {
  const int i   = blockIdx.x;
  const int tid = threadIdx.x;
  const int s0 = row_start[i], s1 = row_start[i + 1];

  float acc = 0.f;
  int j = s0;
  for (; j + 3 < s1; j += 4) {
    int sA = csr_src[j], sB = csr_src[j + 1], sC = csr_src[j + 2], sD = csr_src[j + 3];
    float vA = xws[(size_t)sA * OUTC + tid];
    float vB = xws[(size_t)sB * OUTC + tid];
    float vC = xws[(size_t)sC * OUTC + tid];
    float vD = xws[(size_t)sD * OUTC + tid];
    acc += vA + vB + vC + vD;
  }
  for (; j < s1; j++) {
    int s = csr_src[j];
    acc += xws[(size_t)s * OUTC + tid];
  }
  float zz = dis[i] * (acc + xws[(size_t)i * OUTC + tid]) + b[tid];
  z[(size_t)i * OUTC + tid] = fmaxf(zz, 0.f);   // ReLU folded
}

// ---------------- decode: z @ W_dec -> softmax (z already relu'd) ----------------
__global__ __launch_bounds__(256) void k_decode(const float* __restrict__ z,
                                                const float* __restrict__ Wd,
                                                float* __restrict__ out) {
  __shared__ float zs[16 * 128];   // 8 KB
  __shared__ float lg[16 * 512];   // 32 KB
  const int tid = threadIdx.x;
  const size_t nb = (size_t)blockIdx.x * 16;

  const float4* zsrc = (const float4*)(z + nb * OUTC);
#pragma unroll
  for (int i = 0; i < 2; i++) {
    float4 v = zsrc[tid + i * 256];
    *(float4*)&zs[(tid + i * 256) * 4] = v;
  }
  __syncthreads();

  float acc0[16], acc1[16];
#pragma unroll
  for (int n = 0; n < 16; n++) { acc0[n] = 0.f; acc1[n] = 0.f; }

  for (int k = 0; k < 128; k += 4) {
    float w0[4], w1[4];
#pragma unroll
    for (int j = 0; j < 4; j++) {
      w0[j] = Wd[(size_t)(k + j) * INC + tid];
      w1[j] = Wd[(size_t)(k + j) * INC + tid + 256];
    }
#pragma unroll
    for (int n = 0; n < 16; n++) {
      float4 zk = *(float4*)&zs[n * OUTC + k];
      acc0[n] += zk.x * w0[0] + zk.y * w0[1] + zk.z * w0[2] + zk.w * w0[3];
      acc1[n] += zk.x * w1[0] + zk.y * w1[1] + zk.z * w1[2] + zk.w * w1[3];
    }
  }

#pragma unroll
  for (int n = 0; n < 16; n++) {
    lg[n * INC + tid]       = acc0[n];
    lg[n * INC + tid + 256] = acc1[n];
  }
  __syncthreads();

  const int wid = tid >> 6, lane = tid & 63;
  for (int n = wid * 4; n < wid * 4 + 4; n++) {
    float v[8]; float m = -1e30f;
#pragma unroll
    for (int i = 0; i < 8; i++) { v[i] = lg[n * INC + lane + i * 64]; m = fmaxf(m, v[i]); }
#pragma unroll
    for (int off = 32; off > 0; off >>= 1) m = fmaxf(m, __shfl_xor(m, off));
    float ssum = 0.f;
#pragma unroll
    for (int i = 0; i < 8; i++) { v[i] = __expf(v[i] - m); ssum += v[i]; }
#pragma unroll
    for (int off = 32; off > 0; off >>= 1) ssum += __shfl_xor(ssum, off);
    float inv = 1.0f / ssum;
    float* op = out + (nb + n) * INC;
#pragma unroll
    for (int i = 0; i < 8; i++) op[lane + i * 64] = v[i] * inv;
  }
}

// ---------------- launch ----------------
extern "C" void kernel_launch(void* const* d_in, const int* in_sizes, int n_in,
                              void* d_out, int out_size, void* d_ws, size_t ws_size,
                              hipStream_t stream) {
  const float* x     = (const float*)d_in[0];
  const int*   ei    = (const int*)d_in[1];
  const float* W_enc = (const float*)d_in[2];
  const float* b_enc = (const float*)d_in[3];
  const float* W_dec = (const float*)d_in[4];
  float* out = (float*)d_out;

  const int E = in_sizes[1] / 2;
  const int* esrc = ei;
  const int* edst = ei + E;

  uint8_t* ws = (uint8_t*)d_ws;
  int*   cnt       = (int*)  (ws + 0);                 // 200 KB
  float* dis       = (float*)(ws + (256 << 10));       // 200 KB
  int*   row_start = (int*)  (ws + (512 << 10));       // 200 KB (+4)
  int*   cursor    = (int*)  (ws + (768 << 10));       // 200 KB
  int*   csr_src   = (int*)  (ws + (1 << 20));         // 6.4 MB
  float* xws       = (float*)(ws + (8 << 20));         // 25.6 MB
  float* z         = (float*)(ws + (34 << 20));        // 25.6 MB
                                                       // end ~60 MB

  k_zero_cnt <<<(NN + 255) / 256, 256, 0, stream>>>(cnt);
  k_count    <<<(E + 255) / 256, 256, 0, stream>>>(edst, E, cnt);
  k_dis      <<<(NN + 255) / 256, 256, 0, stream>>>(cnt, dis);
  k_scan     <<<1, SCAN_T, 0, stream>>>(cnt, row_start, cursor);
  k_fill     <<<(E + 255) / 256, 256, 0, stream>>>(esrc, edst, E, cursor, csr_src);
  k_gemm1    <<<(NN + 63) / 64, 256, 0, stream>>>(x, W_enc, dis, xws);
  k_aggregate<<<NN, 128, 0, stream>>>(xws, dis, row_start, csr_src, b_enc, z);
  k_decode   <<<NN / 16, 256, 0, stream>>>(z, W_dec, out);
}

// Round 4
// 600.560 us; speedup vs baseline: 5.2925x; 1.3308x over previous
//
#include <hip/hip_runtime.h>
#include <stdint.h>

#define NN   50000
#define INC  512
#define OUTC 128
#define SCAN_T  1024
#define SCAN_CH 49   // 1024*49 = 50176 >= NN

typedef unsigned int  uint;
typedef unsigned short u16;
typedef short bf16x8 __attribute__((ext_vector_type(8)));
typedef float f32x4  __attribute__((ext_vector_type(4)));
typedef u16   u16x8  __attribute__((ext_vector_type(8)));
typedef u16   u16x4  __attribute__((ext_vector_type(4)));

__device__ __forceinline__ u16 f2bf(float f) {        // RNE f32->bf16
  uint u = __float_as_uint(f);
  u += 0x7fffu + ((u >> 16) & 1u);
  return (u16)(u >> 16);
}
__device__ __forceinline__ float bflo(uint v) { return __uint_as_float(v << 16); }
__device__ __forceinline__ float bfhi(uint v) { return __uint_as_float(v & 0xffff0000u); }

// ---------------- degree / norm ----------------
__global__ __launch_bounds__(256) void k_zero_cnt(int* __restrict__ c) {
  int i = blockIdx.x * 256 + threadIdx.x;
  if (i < NN) c[i] = 0;
}
__global__ __launch_bounds__(256) void k_count(const int* __restrict__ dst, int E,
                                               int* __restrict__ cnt) {
  int e = blockIdx.x * 256 + threadIdx.x;
  if (e < E) atomicAdd(&cnt[dst[e]], 1);
}
__global__ __launch_bounds__(256) void k_dis(const int* __restrict__ cnt,
                                             float* __restrict__ dis) {
  int i = blockIdx.x * 256 + threadIdx.x;
  if (i < NN) dis[i] = rsqrtf((float)(cnt[i] + 1));
}

// ---------------- CSR build ----------------
__global__ __launch_bounds__(SCAN_T) void k_scan(const int* __restrict__ cnt,
                                                 int* __restrict__ row_start,
                                                 int* __restrict__ cursor) {
  __shared__ int part[SCAN_T];
  const int tid = threadIdx.x;
  const int base = tid * SCAN_CH;
  int s = 0;
  for (int j = 0; j < SCAN_CH; j++) {
    int idx = base + j;
    if (idx < NN) s += cnt[idx];
  }
  part[tid] = s;
  __syncthreads();
  for (int off = 1; off < SCAN_T; off <<= 1) {
    int v = (tid >= off) ? part[tid - off] : 0;
    __syncthreads();
    part[tid] += v;
    __syncthreads();
  }
  int run = (tid == 0) ? 0 : part[tid - 1];
  for (int j = 0; j < SCAN_CH; j++) {
    int idx = base + j;
    if (idx < NN) {
      row_start[idx] = run;
      cursor[idx]    = run;
      run += cnt[idx];
    }
  }
  if (tid == SCAN_T - 1) row_start[NN] = run;
}

__global__ __launch_bounds__(256) void k_fill(const int* __restrict__ src,
                                              const int* __restrict__ dst, int E,
                                              int* __restrict__ cursor,
                                              int* __restrict__ csr_src) {
  int e = blockIdx.x * 256 + threadIdx.x;
  if (e >= E) return;
  int d = dst[e];
  int pos = atomicAdd(&cursor[d], 1);
  csr_src[pos] = src[e];
}

// ---------------- weight prep: transpose + bf16 + pre-swizzle ----------------
// Output layout (both): [4 chunks][128 rows][128 k] bf16, row stride 256 B,
// within chunk: byte = (row*256 + k*2) ^ ((row&7)<<4).  Chunk = 32768 B.
// enc: chunks along K (k-quarter q = k>>7), rows = n (0..127)
__global__ __launch_bounds__(256) void k_prep_enc(const float* __restrict__ W,   // [512][128]
                                                  uint8_t* __restrict__ outw) {
  __shared__ float t[32][128];
  const int tid = threadIdx.x;
  const int k0 = blockIdx.x * 32;
#pragma unroll
  for (int r = 0; r < 16; ++r) {
    int e = r * 256 + tid;           // 0..4095
    int kk = e >> 7, n = e & 127;
    t[kk][n] = W[(size_t)(k0 + kk) * 128 + n];
  }
  __syncthreads();
#pragma unroll
  for (int it = 0; it < 2; ++it) {
    int item = it * 256 + tid;       // 0..511
    int n = item & 127, kc = item >> 7;   // kc: 0..3 (8 k each)
    int kg = k0 + kc * 8;
    int q = kg >> 7, kin = kg & 127;
    u16x8 p;
#pragma unroll
    for (int j = 0; j < 8; ++j) p[j] = f2bf(t[kc * 8 + j][n]);
    *(u16x8*)(outw + q * 32768 + ((((uint)n * 256) + (uint)kin * 2) ^ (uint)((n & 7) << 4))) = p;
  }
}
// dec: chunks along N (c = n>>7), rows = n&127, k = 0..127
__global__ __launch_bounds__(256) void k_prep_dec(const float* __restrict__ W,   // [128][512]
                                                  uint8_t* __restrict__ outw) {
  __shared__ float t[128][32];
  const int tid = threadIdx.x;
  const int n0 = blockIdx.x * 32;
#pragma unroll
  for (int r = 0; r < 16; ++r) {
    int e = r * 256 + tid;           // 0..4095
    int k = e >> 5, nl = e & 31;
    t[k][nl] = W[(size_t)k * 512 + n0 + nl];
  }
  __syncthreads();
#pragma unroll
  for (int it = 0; it < 2; ++it) {
    int item = it * 256 + tid;       // 0..511
    int nl = item & 31, kc = item >> 5;   // kc: 0..15 (8 k each)
    int n = n0 + nl;
    int c = n >> 7, nin = n & 127;
    u16x8 p;
#pragma unroll
    for (int j = 0; j < 8; ++j) p[j] = f2bf(t[kc * 8 + j][nl]);
    *(u16x8*)(outw + c * 32768 + ((((uint)nin * 256) + (uint)kc * 16) ^ (uint)((nin & 7) << 4))) = p;
  }
}

// ---------------- GEMM1 (MFMA): xws = bf16( (x @ W_enc) * dis[row] ) ----------------
// 128x128 tile, 4 waves x (32 rows x 128 cols). LDS: W-chunk 32KB + x-tile 16KB = 48KB.
__global__ __launch_bounds__(256, 2) void k_gemm1(const float* __restrict__ x,
                                                  const uint8_t* __restrict__ WtE,
                                                  const float* __restrict__ dis,
                                                  u16* __restrict__ xws) {
  __shared__ __align__(16) uint8_t lds[49152];
  uint8_t* WL = lds;            // 32768
  uint8_t* XL = lds + 32768;    // 16384: [128 rows][64 k] bf16 swizzled
  const int tid = threadIdx.x, lane = tid & 63, wv = tid >> 6;
  const int lane15 = lane & 15, laneh = lane >> 4;
  const int rb = blockIdx.x * 128;

  f32x4 acc[2][8];
#pragma unroll
  for (int m = 0; m < 2; ++m)
#pragma unroll
    for (int n = 0; n < 8; ++n) acc[m][n] = (f32x4){0.f, 0.f, 0.f, 0.f};

  const int srow = tid >> 1;
  int grow = rb + srow; if (grow >= NN) grow = NN - 1;
  const int khalf = (tid & 1) * 32;
  const uint xb  = (uint)srow * 128 + (uint)khalf * 2;
  const uint xsw = (uint)((srow & 7) << 4);
  const int ar0 = wv * 32 + lane15, ar1 = ar0 + 16;

  for (int q = 0; q < 4; ++q) {           // K quarters of 128
    __syncthreads();
    { const u16x8* s = (const u16x8*)(WtE + q * 32768);
      u16x8* d = (u16x8*)WL;
#pragma unroll
      for (int i = 0; i < 8; ++i) d[tid + i * 256] = s[tid + i * 256]; }
#pragma unroll
    for (int step = 0; step < 2; ++step) {  // BK = 64
      if (step) __syncthreads();
      // stage x tile (f32 -> bf16, swizzled)
      const float4* xs = (const float4*)(x + (size_t)grow * INC + q * 128 + step * 64 + khalf);
      float4 v[8];
#pragma unroll
      for (int j = 0; j < 8; ++j) v[j] = xs[j];
#pragma unroll
      for (int j = 0; j < 8; ++j) {
        u16x4 p; p.x = f2bf(v[j].x); p.y = f2bf(v[j].y); p.z = f2bf(v[j].z); p.w = f2bf(v[j].w);
        *(u16x4*)(XL + ((xb + j * 8) ^ xsw)) = p;
      }
      __syncthreads();
#pragma unroll
      for (int kk = 0; kk < 2; ++kk) {     // k-slices of 32
        bf16x8 a0 = *(const bf16x8*)(XL + (((uint)ar0 * 128 + kk * 64 + laneh * 16) ^ (uint)((ar0 & 7) << 4)));
        bf16x8 a1 = *(const bf16x8*)(XL + (((uint)ar1 * 128 + kk * 64 + laneh * 16) ^ (uint)((ar1 & 7) << 4)));
#pragma unroll
        for (int nf = 0; nf < 8; ++nf) {
          int n = nf * 16 + lane15;
          bf16x8 b = *(const bf16x8*)(WL + (((uint)n * 256 + step * 128 + kk * 64 + laneh * 16) ^ (uint)((n & 7) << 4)));
          acc[0][nf] = __builtin_amdgcn_mfma_f32_16x16x32_bf16(a0, b, acc[0][nf], 0, 0, 0);
          acc[1][nf] = __builtin_amdgcn_mfma_f32_16x16x32_bf16(a1, b, acc[1][nf], 0, 0, 0);
        }
      }
    }
  }
  // epilogue: scale by dis, store bf16
#pragma unroll
  for (int m = 0; m < 2; ++m) {
#pragma unroll
    for (int r = 0; r < 4; ++r) {
      int row = rb + wv * 32 + m * 16 + laneh * 4 + r;
      if (row < NN) {
        float dv = dis[row];
#pragma unroll
        for (int nf = 0; nf < 8; ++nf)
          xws[(size_t)row * 128 + nf * 16 + lane15] = f2bf(acc[m][nf][r] * dv);
      }
    }
  }
}

// ---------------- aggregate: z = bf16(relu(dis*(sum + self) + b)), pre-swizzled ----------------
__global__ __launch_bounds__(64) void k_aggregate(const u16* __restrict__ xws,
                                                  const float* __restrict__ dis,
                                                  const int* __restrict__ row_start,
                                                  const int* __restrict__ csr_src,
                                                  const float* __restrict__ bias,
                                                  uint8_t* __restrict__ zsw) {
  const int i = blockIdx.x, lane = threadIdx.x;
  const int s0 = row_start[i], s1 = row_start[i + 1];
  float a0 = 0.f, a1 = 0.f;
  int j = s0;
  for (; j + 3 < s1; j += 4) {
    int i0 = csr_src[j], i1 = csr_src[j + 1], i2 = csr_src[j + 2], i3 = csr_src[j + 3];
    uint v0 = *(const uint*)(xws + (size_t)i0 * 128 + lane * 2);
    uint v1 = *(const uint*)(xws + (size_t)i1 * 128 + lane * 2);
    uint v2 = *(const uint*)(xws + (size_t)i2 * 128 + lane * 2);
    uint v3 = *(const uint*)(xws + (size_t)i3 * 128 + lane * 2);
    a0 += bflo(v0) + bflo(v1) + bflo(v2) + bflo(v3);
    a1 += bfhi(v0) + bfhi(v1) + bfhi(v2) + bfhi(v3);
  }
  for (; j < s1; ++j) {
    uint v = *(const uint*)(xws + (size_t)csr_src[j] * 128 + lane * 2);
    a0 += bflo(v); a1 += bfhi(v);
  }
  uint vs = *(const uint*)(xws + (size_t)i * 128 + lane * 2);
  float di = dis[i];
  float2 bb = *(const float2*)(bias + lane * 2);
  float z0 = fmaxf(di * (a0 + bflo(vs)) + bb.x, 0.f);
  float z1 = fmaxf(di * (a1 + bfhi(vs)) + bb.y, 0.f);
  uint pk = (uint)f2bf(z0) | ((uint)f2bf(z1) << 16);
  *(uint*)(zsw + ((((uint)i * 256) + (uint)lane * 4) ^ (uint)((i & 7) << 4))) = pk;
}

// ---------------- decode (MFMA): out = softmax(z @ W_dec) ----------------
// 8 waves x 16 rows = 128 rows/block. K=128 in registers; N=512 in 4 chunks.
// LDS: z-tile 32KB + W-chunk 32KB = 64KB -> 2 blocks/CU.
__global__ __launch_bounds__(512, 2) void k_decode(const uint8_t* __restrict__ zsw,
                                                   const uint8_t* __restrict__ WtD,
                                                   float* __restrict__ out) {
  __shared__ __align__(16) uint8_t lds[65536];
  uint8_t* ZL = lds;            // 32768: [128 rows][128 k] bf16 swizzled
  uint8_t* WL = lds + 32768;    // 32768: [128 n][128 k] bf16 swizzled
  const int tid = threadIdx.x, lane = tid & 63, wv = tid >> 6;
  const int lane15 = lane & 15, laneh = lane >> 4;
  const int rb = blockIdx.x * 128;

  // stage z tile (identity copy, already swizzled)
  { const u16x8* s = (const u16x8*)(zsw + (size_t)rb * 256);
    u16x8* d = (u16x8*)ZL;
#pragma unroll
    for (int i = 0; i < 4; ++i) d[tid + i * 512] = s[tid + i * 512]; }

  f32x4 acc[32];
#pragma unroll
  for (int f = 0; f < 32; ++f) acc[f] = (f32x4){0.f, 0.f, 0.f, 0.f};

  const int zr = wv * 16 + lane15;
  bf16x8 a[4];

#pragma unroll
  for (int c = 0; c < 4; ++c) {          // N chunks of 128
    if (c) __syncthreads();              // protect WL overwrite
    { const u16x8* s = (const u16x8*)(WtD + c * 32768);
      u16x8* d = (u16x8*)WL;
#pragma unroll
      for (int i = 0; i < 4; ++i) d[tid + i * 512] = s[tid + i * 512]; }
    __syncthreads();
    if (c == 0) {
#pragma unroll
      for (int s = 0; s < 4; ++s)
        a[s] = *(const bf16x8*)(ZL + (((uint)zr * 256 + s * 64 + laneh * 16) ^ (uint)((zr & 7) << 4)));
    }
#pragma unroll
    for (int nf = 0; nf < 8; ++nf) {
      int n = nf * 16 + lane15;
      uint nb = (uint)n * 256 + laneh * 16, nsw = (uint)((n & 7) << 4);
#pragma unroll
      for (int s = 0; s < 4; ++s) {
        bf16x8 b = *(const bf16x8*)(WL + ((nb + s * 64) ^ nsw));
        acc[c * 8 + nf] = __builtin_amdgcn_mfma_f32_16x16x32_bf16(a[s], b, acc[c * 8 + nf], 0, 0, 0);
      }
    }
  }

  // softmax over 512 cols, fully in-register (row lives in one 16-lane group)
#pragma unroll
  for (int r = 0; r < 4; ++r) {
    float m = acc[0][r];
#pragma unroll
    for (int f = 1; f < 32; ++f) m = fmaxf(m, acc[f][r]);
    m = fmaxf(m, __shfl_xor(m, 1)); m = fmaxf(m, __shfl_xor(m, 2));
    m = fmaxf(m, __shfl_xor(m, 4)); m = fmaxf(m, __shfl_xor(m, 8));
    float sum = 0.f;
#pragma unroll
    for (int f = 0; f < 32; ++f) { acc[f][r] = __expf(acc[f][r] - m); sum += acc[f][r]; }
    sum += __shfl_xor(sum, 1); sum += __shfl_xor(sum, 2);
    sum += __shfl_xor(sum, 4); sum += __shfl_xor(sum, 8);
    float inv = 1.0f / sum;
    int row = rb + wv * 16 + laneh * 4 + r;
    if (row < NN) {
      float* op = out + (size_t)row * INC + lane15;
#pragma unroll
      for (int f = 0; f < 32; ++f)
        op[(f >> 3) * 128 + (f & 7) * 16] = acc[f][r] * inv;
    }
  }
}

// ---------------- launch ----------------
extern "C" void kernel_launch(void* const* d_in, const int* in_sizes, int n_in,
                              void* d_out, int out_size, void* d_ws, size_t ws_size,
                              hipStream_t stream) {
  const float* x     = (const float*)d_in[0];
  const int*   ei    = (const int*)d_in[1];
  const float* W_enc = (const float*)d_in[2];
  const float* b_enc = (const float*)d_in[3];
  const float* W_dec = (const float*)d_in[4];
  float* out = (float*)d_out;

  const int E = in_sizes[1] / 2;
  const int* esrc = ei;
  const int* edst = ei + E;

  uint8_t* ws = (uint8_t*)d_ws;
  int*    cnt       = (int*)(ws);                  // 200 KB
  float*  dis       = (float*)(ws + 0x40000);      // 200 KB
  int*    row_start = (int*)(ws + 0x80000);        // 200 KB (+4)
  int*    cursor    = (int*)(ws + 0xC0000);        // 200 KB
  int*    csr_src   = (int*)(ws + 0x100000);       // 6.4 MB
  uint8_t* WtE      = ws + 0x800000;               // 128 KB
  uint8_t* WtD      = ws + 0x820000;               // 128 KB
  u16*    xws       = (u16*)(ws + 0x840000);       // 12.8 MB
  uint8_t* zsw      = ws + 0x840000 + 12800000;    // 12.8 MB + tail pad

  k_zero_cnt <<<(NN + 255) / 256, 256, 0, stream>>>(cnt);
  k_count    <<<(E + 255) / 256, 256, 0, stream>>>(edst, E, cnt);
  k_dis      <<<(NN + 255) / 256, 256, 0, stream>>>(cnt, dis);
  k_scan     <<<1, SCAN_T, 0, stream>>>(cnt, row_start, cursor);
  k_fill     <<<(E + 255) / 256, 256, 0, stream>>>(esrc, edst, E, cursor, csr_src);
  k_prep_enc <<<16, 256, 0, stream>>>(W_enc, WtE);
  k_prep_dec <<<16, 256, 0, stream>>>(W_dec, WtD);
  k_gemm1    <<<(NN + 127) / 128, 256, 0, stream>>>(x, WtE, dis, xws);
  k_aggregate<<<NN, 64, 0, stream>>>(xws, dis, row_start, csr_src, b_enc, zsw);
  k_decode   <<<(NN + 127) / 128, 512, 0, stream>>>(zsw, WtD, out);
}